// Round 5
// baseline (128.280 us; speedup 1.0000x reference)
//
#include <hip/hip_runtime.h>
#include <hip/hip_bf16.h>

// ConvDeepSet round 11: R=4 structure (round 10) + 4 waves/SIMD (K-split 4).
//  Postmortem R0-R10: VALU-busy is invariant ~21-27us (exp2 quarter-rate +
//  pack + fma + addressing) and runs at only ~40-55% duty. R9: occupancy
//  without TA fix = no gain. R10: TA fix at 2 waves/SIMD = 44us. Combine:
//  - K-split 4: each wave does 4 tiles (64 rows) x quarter ctx (16 ksteps).
//    4096 waves, grid 1024 = 4 blocks/CU = 4 waves/SIMD. Per-CU TA count
//    and L2 volume unchanged vs R10.
//  - LDS 36KB (fits 4 blocks/CU): sxa staged; sxb computed as -0.25*xa^2.
//  - VGPR <=128 via launch_bounds(256,4): single-slot loads (TLP covers
//    latency, R7 precedent), pointer-increment addressing.
//  - 2-round pairwise reduction (wv^1, wv^2); each wave epilogues 1 tile.

#define N_CTX 2048
#define BATCH 16
#define M_TGT 4096
#define COUT  64
#define RDIM  128

#define WS_CO_BYTES (N_CTX * BATCH * COUT * 2)          // 4 MB
#define WS_SXA_OFF  WS_CO_BYTES                         // 128 KB fp32 (2*sx)
#define WS_SXB_OFF  (WS_SXA_OFF + N_CTX * BATCH * 4)    // 128 KB fp32 (unused by main)
#define WS_WT_OFF   (WS_SXB_OFF + N_CTX * BATCH * 4)    // 16 KB bf16

#define SSCALE 0.8493222f   // sqrt(0.5 * log2(e))

typedef __attribute__((ext_vector_type(8)))  short        bf16x8;
typedef __attribute__((ext_vector_type(4)))  float        floatx4;
typedef __attribute__((ext_vector_type(4)))  unsigned int uint4v;

#if __has_builtin(__builtin_amdgcn_exp2f)
#define EXP2F __builtin_amdgcn_exp2f
#else
#define EXP2F exp2f
#endif

static __device__ __forceinline__ unsigned int pack_bf16(float lo, float hi) {
    __hip_bfloat162 h = __float22bfloat162_rn(make_float2(lo, hi));
    return *reinterpret_cast<unsigned int*>(&h);
}
static __device__ __forceinline__ unsigned short f2bf(float f) {
    __hip_bfloat16 h = __float2bfloat16(f);
    return *reinterpret_cast<unsigned short*>(&h);
}
static __device__ __forceinline__ floatx4 fma4(floatx4 a, float s, floatx4 b) {
    floatx4 r;
    r.x = __builtin_fmaf(a.x, s, b.x);
    r.y = __builtin_fmaf(a.y, s, b.y);
    r.z = __builtin_fmaf(a.z, s, b.z);
    r.w = __builtin_fmaf(a.w, s, b.w);
    return r;
}

__global__ __launch_bounds__(256)
void convdeepset_prep(const float* __restrict__ ci, const float* __restrict__ co,
                      const float* __restrict__ ls, const float* __restrict__ W,
                      unsigned char* __restrict__ ws)
{
    unsigned short* cow = (unsigned short*)ws;
    float*          sxa = (float*)(ws + WS_SXA_OFF);
    float*          sxb = (float*)(ws + WS_SXB_OFF);
    unsigned short* wt  = (unsigned short*)(ws + WS_WT_OFF);
    const int blk = blockIdx.x, tid = threadIdx.x;

    if (blk < 1024) {
        const int g    = blk * 4 + (tid >> 6);
        const int bb   = g & 15;
        const int nblk = g >> 4;           // 0..255
        const int c    = tid & 63;
        const float* rp = co + ((size_t)nblk * 8 * BATCH + bb) * COUT + c;
        unsigned int u[4];
#pragma unroll
        for (int j = 0; j < 4; ++j) {
            const float f0 = rp[(size_t)(2 * j)     * BATCH * COUT];
            const float f1 = rp[(size_t)(2 * j + 1) * BATCH * COUT];
            u[j] = pack_bf16(f0, f1);
        }
        *(uint4v*)&cow[(size_t)bb * 131072 + nblk * 512 + c * 8] = *(uint4v*)u;
    } else if (blk < 1152) {
        const int f = (blk - 1024) * 256 + tid;   // 0..32767
        const int n = f & 2047, bb = f >> 11;
        const float s = SSCALE / ls[0];
        const float v = s * ci[(size_t)n * BATCH + bb];
        sxa[bb * 2048 + n] = v + v;     // 2*sx
        sxb[bb * 2048 + n] = -v * v;    // kept for layout compat (unused)
    } else {
        for (int f = tid; f < 8192; f += 256) {
            const int cp = f & 7, r = (f >> 3) & 127, ch = f >> 10;
            wt[ch * 1024 + r * 8 + cp] = f2bf(W[r * 65 + 1 + ch * 8 + cp]);
        }
    }
}

__global__ __launch_bounds__(256, 4)
void convdeepset_main(const float* __restrict__ ti, const float* __restrict__ ls,
                      const float* __restrict__ W,  const float* __restrict__ bias,
                      const unsigned char* __restrict__ ws, float* __restrict__ out)
{
    __shared__ float sxal[N_CTX];                 //  8 KB: 2*sx (whole ctx)
    __shared__ float xred[4][64][20];             // 20 KB partial-acc exchange
    __shared__ unsigned short vstage[4][1024];    //  8 KB V staging, same-wave
    // 36 KB -> 4 blocks/CU

    const int tid  = threadIdx.x;
    const int lane = tid & 63;
    const int wv   = tid >> 6;        // ctx quarter 0..3
    const int g2   = lane >> 4;       // MFMA k-group 0..3
    const int l15  = lane & 15;
    const int q01  = wv & 1;          // round-1 role

    // XCD swizzle: 2 batches pinned per XCD
    const int xcd = blockIdx.x & 7;
    const int i   = blockIdx.x >> 3;  // 0..127
    const int b   = xcd * 2 + (i & 1);
    const int mt  = i >> 1;           // 0..63
    const int m0  = mt * 64;          // block's 64-row base (all waves share)

    // stage 2*sx table (coalesced float4)
    const float4* sag = (const float4*)(ws + WS_SXA_OFF) + b * (N_CTX / 4);
    ((float4*)sxal)[tid]       = sag[tid];
    ((float4*)sxal)[tid + 256] = sag[tid + 256];

    const float s = SSCALE / ls[0];
    float syv[4];
#pragma unroll
    for (int t = 0; t < 4; ++t)
        syv[t] = s * ti[(size_t)(m0 + t * 16 + l15) * BATCH + b];

    // B-frag base for this wave's ctx quarter (16 ksteps of 32 ctx pts)
    const unsigned short* bp = (const unsigned short*)ws
                             + (size_t)b * 131072 + (size_t)wv * 32768
                             + (g2 << 9) + l15 * 8;
    const float* xap = &sxal[wv * 512 + g2 * 8];

    const short onebf = (short)0x3F80;
    bf16x8 ones;
#pragma unroll
    for (int j = 0; j < 8; ++j) ones[j] = onebf;

    floatx4 acc[4][4], accd[4];
#pragma unroll
    for (int t = 0; t < 4; ++t) {
#pragma unroll
        for (int q = 0; q < 4; ++q)
#pragma unroll
            for (int e = 0; e < 4; ++e) acc[t][q][e] = 0.0f;
#pragma unroll
        for (int e = 0; e < 4; ++e) accd[t][e] = 0.0f;
    }

    __syncthreads();   // sxal visible

    for (int k = 0; k < 16; ++k) {
        const bf16x8 c0 = *(const bf16x8*)(bp);
        const bf16x8 c1 = *(const bf16x8*)(bp + 128);
        const bf16x8 c2 = *(const bf16x8*)(bp + 256);
        const bf16x8 c3 = *(const bf16x8*)(bp + 384);
        bp += 2048;
        const floatx4 xa0 = *(const floatx4*)(xap);
        const floatx4 xa1 = *(const floatx4*)(xap + 4);
        xap += 32;
        const floatx4 xb0 = xa0 * (xa0 * -0.25f);   // -sx^2
        const floatx4 xb1 = xa1 * (xa1 * -0.25f);
#pragma unroll
        for (int t = 0; t < 4; ++t) {
            const float sy = syv[t];
            const floatx4 a0 = fma4(xa0, sy, xb0);
            const floatx4 a1 = fma4(xa1, sy, xb1);
            float kv[8];
            kv[0] = EXP2F(a0.x); kv[1] = EXP2F(a0.y);
            kv[2] = EXP2F(a0.z); kv[3] = EXP2F(a0.w);
            kv[4] = EXP2F(a1.x); kv[5] = EXP2F(a1.y);
            kv[6] = EXP2F(a1.z); kv[7] = EXP2F(a1.w);
            uint4v aw;
#pragma unroll
            for (int q = 0; q < 4; ++q)
                aw[q] = pack_bf16(kv[2 * q], kv[2 * q + 1]);
            const bf16x8 av = __builtin_bit_cast(bf16x8, aw);
            acc[t][0] = __builtin_amdgcn_mfma_f32_16x16x32_bf16(av, c0, acc[t][0], 0, 0, 0);
            acc[t][1] = __builtin_amdgcn_mfma_f32_16x16x32_bf16(av, c1, acc[t][1], 0, 0, 0);
            acc[t][2] = __builtin_amdgcn_mfma_f32_16x16x32_bf16(av, c2, acc[t][2], 0, 0, 0);
            acc[t][3] = __builtin_amdgcn_mfma_f32_16x16x32_bf16(av, c3, acc[t][3], 0, 0, 0);
            accd[t]   = __builtin_amdgcn_mfma_f32_16x16x32_bf16(av, ones, accd[t], 0, 0, 0);
        }
    }

    // ---- round 1: pair wv^1 (quarters {0,1} and {2,3}) ----
    // even wave keeps tiles 0,1; odd keeps 2,3. Two sub-rounds like round 10.
#pragma unroll
    for (int j = 0; j < 2; ++j) {
        float* xw = &xred[wv][lane][0];
        if (q01 == 0) {           // send tile 2+j
            *(floatx4*)&xw[0]  = acc[2 + j][0];
            *(floatx4*)&xw[4]  = acc[2 + j][1];
            *(floatx4*)&xw[8]  = acc[2 + j][2];
            *(floatx4*)&xw[12] = acc[2 + j][3];
            *(floatx4*)&xw[16] = accd[2 + j];
        } else {                  // send tile j
            *(floatx4*)&xw[0]  = acc[j][0];
            *(floatx4*)&xw[4]  = acc[j][1];
            *(floatx4*)&xw[8]  = acc[j][2];
            *(floatx4*)&xw[12] = acc[j][3];
            *(floatx4*)&xw[16] = accd[j];
        }
        __syncthreads();
        const float* xr = &xred[wv ^ 1][lane][0];
        if (q01 == 0) {           // receive tile j
            acc[j][0] += *(const floatx4*)&xr[0];
            acc[j][1] += *(const floatx4*)&xr[4];
            acc[j][2] += *(const floatx4*)&xr[8];
            acc[j][3] += *(const floatx4*)&xr[12];
            accd[j]   += *(const floatx4*)&xr[16];
        } else {                  // receive tile 2+j
            acc[2 + j][0] += *(const floatx4*)&xr[0];
            acc[2 + j][1] += *(const floatx4*)&xr[4];
            acc[2 + j][2] += *(const floatx4*)&xr[8];
            acc[2 + j][3] += *(const floatx4*)&xr[12];
            accd[2 + j]   += *(const floatx4*)&xr[16];
        }
        __syncthreads();
    }

    // ---- round 2: pair wv^2. send: w0->t1 w1->t3 w2->t0 w3->t2; keep own ----
    {
        float* xw = &xred[wv][lane][0];
        const int st = (wv == 0) ? 1 : (wv == 1) ? 3 : (wv == 2) ? 0 : 2;
        if (st == 0)      { *(floatx4*)&xw[0] = acc[0][0]; *(floatx4*)&xw[4] = acc[0][1]; *(floatx4*)&xw[8] = acc[0][2]; *(floatx4*)&xw[12] = acc[0][3]; *(floatx4*)&xw[16] = accd[0]; }
        else if (st == 1) { *(floatx4*)&xw[0] = acc[1][0]; *(floatx4*)&xw[4] = acc[1][1]; *(floatx4*)&xw[8] = acc[1][2]; *(floatx4*)&xw[12] = acc[1][3]; *(floatx4*)&xw[16] = accd[1]; }
        else if (st == 2) { *(floatx4*)&xw[0] = acc[2][0]; *(floatx4*)&xw[4] = acc[2][1]; *(floatx4*)&xw[8] = acc[2][2]; *(floatx4*)&xw[12] = acc[2][3]; *(floatx4*)&xw[16] = accd[2]; }
        else              { *(floatx4*)&xw[0] = acc[3][0]; *(floatx4*)&xw[4] = acc[3][1]; *(floatx4*)&xw[8] = acc[3][2]; *(floatx4*)&xw[12] = acc[3][3]; *(floatx4*)&xw[16] = accd[3]; }
        __syncthreads();
        const float* xr = &xred[wv ^ 2][lane][0];
        const int rt = (wv == 0) ? 0 : (wv == 1) ? 2 : (wv == 2) ? 1 : 3;
        if (rt == 0)      { acc[0][0] += *(const floatx4*)&xr[0]; acc[0][1] += *(const floatx4*)&xr[4]; acc[0][2] += *(const floatx4*)&xr[8]; acc[0][3] += *(const floatx4*)&xr[12]; accd[0] += *(const floatx4*)&xr[16]; }
        else if (rt == 1) { acc[1][0] += *(const floatx4*)&xr[0]; acc[1][1] += *(const floatx4*)&xr[4]; acc[1][2] += *(const floatx4*)&xr[8]; acc[1][3] += *(const floatx4*)&xr[12]; accd[1] += *(const floatx4*)&xr[16]; }
        else if (rt == 2) { acc[2][0] += *(const floatx4*)&xr[0]; acc[2][1] += *(const floatx4*)&xr[4]; acc[2][2] += *(const floatx4*)&xr[8]; acc[2][3] += *(const floatx4*)&xr[12]; accd[2] += *(const floatx4*)&xr[16]; }
        else              { acc[3][0] += *(const floatx4*)&xr[0]; acc[3][1] += *(const floatx4*)&xr[4]; acc[3][2] += *(const floatx4*)&xr[8]; acc[3][3] += *(const floatx4*)&xr[12]; accd[3] += *(const floatx4*)&xr[16]; }
    }

    // ---- epilogue: wave owns tile town = {w0:0, w1:2, w2:1, w3:3} ----
    const unsigned short* wtg = (const unsigned short*)(ws + WS_WT_OFF);

    auto epi = [&](const floatx4 (&a)[4], const floatx4 ad, float syt, int t) {
        const float sysq = syt * syt;
        const int   mrow = m0 + t * 16;
        float dt[4], ff[4];
#pragma unroll
        for (int reg = 0; reg < 4; ++reg) {
            const int m   = (lane >> 4) * 4 + reg;   // C/D map row
            const float ysq = __shfl(sysq, m, 64);   // lane m holds row m's y^2
            const float e   = EXP2F(-ysq);
            dt[reg] = ad[reg] * e;
            ff[reg] = e / (dt[reg] + 1e-8f);
        }
        unsigned short* vs = vstage[wv];
#pragma unroll
        for (int reg = 0; reg < 4; ++reg) {
            const int m = (lane >> 4) * 4 + reg;
#pragma unroll
            for (int q = 0; q < 4; ++q) {
                const int c = q * 16 + l15;
                vs[(c >> 3) * 128 + m * 8 + (c & 7)] = f2bf(a[q][reg]);
            }
        }
        floatx4 pacc[8];
#pragma unroll
        for (int r8 = 0; r8 < 8; ++r8)
#pragma unroll
            for (int e = 0; e < 4; ++e) pacc[r8][e] = 0.0f;
#pragma unroll
        for (int s2 = 0; s2 < 2; ++s2) {
            const int ch = s2 * 4 + g2;
            const bf16x8 avp = *(const bf16x8*)&vs[ch * 128 + l15 * 8];
#pragma unroll
            for (int r8 = 0; r8 < 8; ++r8) {
                const bf16x8 bvp = *(const bf16x8*)&wtg[ch * 1024 + (r8 * 16 + l15) * 8];
                pacc[r8] = __builtin_amdgcn_mfma_f32_16x16x32_bf16(avp, bvp, pacc[r8], 0, 0, 0);
            }
        }
#pragma unroll
        for (int r8 = 0; r8 < 8; ++r8) {
            const int r = r8 * 16 + l15;
            const float w0v = W[r * 65];
            const float bv  = bias[r];
#pragma unroll
            for (int reg = 0; reg < 4; ++reg) {
                const int m = (lane >> 4) * 4 + reg;
                out[((size_t)(mrow + m) * BATCH + b) * RDIM + r]
                    = pacc[r8][reg] * ff[reg] + dt[reg] * w0v + bv;
            }
        }
    };

    if (wv == 0)      epi(acc[0], accd[0], syv[0], 0);
    else if (wv == 1) epi(acc[2], accd[2], syv[2], 2);
    else if (wv == 2) epi(acc[1], accd[1], syv[1], 1);
    else              epi(acc[3], accd[3], syv[3], 3);
}

extern "C" void kernel_launch(void* const* d_in, const int* in_sizes, int n_in,
                              void* d_out, int out_size, void* d_ws, size_t ws_size,
                              hipStream_t stream) {
    const float* ci   = (const float*)d_in[0];  // context_in  (N,B,1)
    const float* co   = (const float*)d_in[1];  // context_out (N,B,64)
    const float* ti   = (const float*)d_in[2];  // target_in   (M,B,1)
    const float* ls   = (const float*)d_in[3];  // lengthscale (1,)
    const float* W    = (const float*)d_in[4];  // (128,65)
    const float* bias = (const float*)d_in[5];  // (128,)
    float* o = (float*)d_out;                   // (M,B,128)
    (void)in_sizes; (void)n_in; (void)out_size; (void)ws_size;

    convdeepset_prep<<<1153, 256, 0, stream>>>(ci, co, ls, W, (unsigned char*)d_ws);
    convdeepset_main<<<1024, 256, 0, stream>>>(
        ti, ls, W, bias, (const unsigned char*)d_ws, o);
}

// Round 6
// 113.418 us; speedup vs baseline: 1.1310x; 1.1310x over previous
//
#include <hip/hip_runtime.h>
#include <hip/hip_bf16.h>

// ConvDeepSet round 12: R10 base + hardware v_cvt_pk_bf16_f32 packing.
//  R11 postmortem: launch_bounds(256,4) spilled (FETCH/WRITE +35MB scratch),
//  53us > R10's 44us. Revert to R10 structure (64m/wave, K-split 2,
//  2 blocks/CU, reg double-buffer, no spill).
//  Single change this round: all fp32->bf16 conversions via inline-asm
//  v_cvt_pk_bf16_f32 (1 instr / 2 values). Theory: __float22bfloat162_rn
//  lowers to ~6-op software RNE per value; 32 conversions/kstep => ~200
//  extra VALU ops/kstep, matching the measured 2x VALU-busy vs hand count
//  that has been invariant across ALL structures (R0-R11).

#define N_CTX 2048
#define BATCH 16
#define M_TGT 4096
#define COUT  64
#define RDIM  128

#define WS_CO_BYTES (N_CTX * BATCH * COUT * 2)          // 4 MB
#define WS_SXA_OFF  WS_CO_BYTES                         // 128 KB fp32 (2*sx)
#define WS_SXB_OFF  (WS_SXA_OFF + N_CTX * BATCH * 4)    // 128 KB fp32 (-sx^2)
#define WS_WT_OFF   (WS_SXB_OFF + N_CTX * BATCH * 4)    // 16 KB bf16

#define SSCALE 0.8493222f   // sqrt(0.5 * log2(e))

typedef __attribute__((ext_vector_type(8)))  short        bf16x8;
typedef __attribute__((ext_vector_type(4)))  float        floatx4;
typedef __attribute__((ext_vector_type(4)))  unsigned int uint4v;

#if __has_builtin(__builtin_amdgcn_exp2f)
#define EXP2F __builtin_amdgcn_exp2f
#else
#define EXP2F exp2f
#endif

// HW bf16 pack: D[15:0]=bf16(lo), D[31:16]=bf16(hi). One VALU instr.
static __device__ __forceinline__ unsigned int pack_bf16(float lo, float hi) {
    unsigned int r;
    asm("v_cvt_pk_bf16_f32 %0, %1, %2" : "=v"(r) : "v"(lo), "v"(hi));
    return r;
}
static __device__ __forceinline__ unsigned short f2bf(float f) {
    unsigned int r;
    asm("v_cvt_pk_bf16_f32 %0, %1, %1" : "=v"(r) : "v"(f));
    return (unsigned short)r;
}

__global__ __launch_bounds__(256)
void convdeepset_prep(const float* __restrict__ ci, const float* __restrict__ co,
                      const float* __restrict__ ls, const float* __restrict__ W,
                      unsigned char* __restrict__ ws)
{
    unsigned short* cow = (unsigned short*)ws;
    float*          sxa = (float*)(ws + WS_SXA_OFF);
    float*          sxb = (float*)(ws + WS_SXB_OFF);
    unsigned short* wt  = (unsigned short*)(ws + WS_WT_OFF);
    const int blk = blockIdx.x, tid = threadIdx.x;

    if (blk < 1024) {
        const int g    = blk * 4 + (tid >> 6);
        const int bb   = g & 15;
        const int nblk = g >> 4;           // 0..255
        const int c    = tid & 63;
        const float* rp = co + ((size_t)nblk * 8 * BATCH + bb) * COUT + c;
        unsigned int u[4];
#pragma unroll
        for (int j = 0; j < 4; ++j) {
            const float f0 = rp[(size_t)(2 * j)     * BATCH * COUT];
            const float f1 = rp[(size_t)(2 * j + 1) * BATCH * COUT];
            u[j] = pack_bf16(f0, f1);
        }
        *(uint4v*)&cow[(size_t)bb * 131072 + nblk * 512 + c * 8] = *(uint4v*)u;
    } else if (blk < 1152) {
        const int f = (blk - 1024) * 256 + tid;   // 0..32767
        const int n = f & 2047, bb = f >> 11;
        const float s = SSCALE / ls[0];
        const float v = s * ci[(size_t)n * BATCH + bb];
        sxa[bb * 2048 + n] = v + v;     // 2*sx
        sxb[bb * 2048 + n] = -v * v;    // -sx^2
    } else {
        for (int f = tid; f < 8192; f += 256) {
            const int cp = f & 7, r = (f >> 3) & 127, ch = f >> 10;
            wt[ch * 1024 + r * 8 + cp] = f2bf(W[r * 65 + 1 + ch * 8 + cp]);
        }
    }
}

struct Slot {
    bf16x8  c0, c1, c2, c3;
    floatx4 xa0, xa1, xb0, xb1;
};

__global__ __launch_bounds__(256, 2)
void convdeepset_main(const float* __restrict__ ti, const float* __restrict__ ls,
                      const float* __restrict__ W,  const float* __restrict__ bias,
                      const unsigned char* __restrict__ ws, float* __restrict__ out)
{
    __shared__ float sxal[N_CTX];                 //  8 KB: 2*sx (whole ctx)
    __shared__ float sxbl[N_CTX];                 //  8 KB: -sx^2
    __shared__ float xred[4][64][20];             // 20 KB partial-acc exchange
    __shared__ unsigned short vstage[4][2][1024]; // 16 KB V staging, same-wave
    // 52 KB -> 2 blocks/CU

    const int tid  = threadIdx.x;
    const int lane = tid & 63;
    const int wv   = tid >> 6;        // 0..3
    const int g2   = lane >> 4;       // MFMA k-group 0..3
    const int l15  = lane & 15;
    const int wpr  = wv >> 1;         // team (row group) 0..1
    const int half = wv & 1;          // ctx half 0..1

    // XCD swizzle: 2 batches pinned per XCD
    const int xcd = blockIdx.x & 7;
    const int i   = blockIdx.x >> 3;  // 0..63
    const int b   = xcd * 2 + (i & 1);
    const int mt  = i >> 1;           // 0..31
    const int m0  = mt * 128 + wpr * 64;   // this wave's 64-row base

    // stage x tables (coalesced float4)
    const float4* sag = (const float4*)(ws + WS_SXA_OFF) + b * (N_CTX / 4);
    const float4* sbg = (const float4*)(ws + WS_SXB_OFF) + b * (N_CTX / 4);
    ((float4*)sxal)[tid]       = sag[tid];
    ((float4*)sxal)[tid + 256] = sag[tid + 256];
    ((float4*)sxbl)[tid]       = sbg[tid];
    ((float4*)sxbl)[tid + 256] = sbg[tid + 256];

    const float s = SSCALE / ls[0];
    float syv[4];
#pragma unroll
    for (int t = 0; t < 4; ++t)
        syv[t] = s * ti[(size_t)(m0 + t * 16 + l15) * BATCH + b];

    // B-frag base for this wave's ctx half (32 ksteps of 32 ctx pts)
    const unsigned short* cowb = (const unsigned short*)ws
                               + (size_t)b * 131072 + (size_t)half * 65536;
    const int xoff = half * 1024;     // float offset into sxal/sxbl

    const short onebf = (short)0x3F80;
    bf16x8 ones;
#pragma unroll
    for (int j = 0; j < 8; ++j) ones[j] = onebf;

    floatx4 acc[4][4], accd[4];
#pragma unroll
    for (int t = 0; t < 4; ++t) {
#pragma unroll
        for (int q = 0; q < 4; ++q)
#pragma unroll
            for (int e = 0; e < 4; ++e) acc[t][q][e] = 0.0f;
#pragma unroll
        for (int e = 0; e < 4; ++e) accd[t][e] = 0.0f;
    }

    auto loadk = [&](Slot& S, int k) {
        const unsigned short* bp = cowb + ((k * 4 + g2) << 9) + l15 * 8;
        S.c0 = *(const bf16x8*)(bp);
        S.c1 = *(const bf16x8*)(bp + 128);
        S.c2 = *(const bf16x8*)(bp + 256);
        S.c3 = *(const bf16x8*)(bp + 384);
        const float* ap  = &sxal[xoff + k * 32 + g2 * 8];
        const float* bpx = &sxbl[xoff + k * 32 + g2 * 8];
        S.xa0 = *(const floatx4*)(ap);
        S.xa1 = *(const floatx4*)(ap + 4);
        S.xb0 = *(const floatx4*)(bpx);
        S.xb1 = *(const floatx4*)(bpx + 4);
    };

    auto compute = [&](const Slot& S) {
#pragma unroll
        for (int t = 0; t < 4; ++t) {
            const float sy = syv[t];
            const floatx4 a0 = S.xa0 * sy + S.xb0;
            const floatx4 a1 = S.xa1 * sy + S.xb1;
            float kv[8];
            kv[0] = EXP2F(a0.x); kv[1] = EXP2F(a0.y);
            kv[2] = EXP2F(a0.z); kv[3] = EXP2F(a0.w);
            kv[4] = EXP2F(a1.x); kv[5] = EXP2F(a1.y);
            kv[6] = EXP2F(a1.z); kv[7] = EXP2F(a1.w);
            uint4v aw;
#pragma unroll
            for (int q = 0; q < 4; ++q)
                aw[q] = pack_bf16(kv[2 * q], kv[2 * q + 1]);
            const bf16x8 av = __builtin_bit_cast(bf16x8, aw);
            acc[t][0] = __builtin_amdgcn_mfma_f32_16x16x32_bf16(av, S.c0, acc[t][0], 0, 0, 0);
            acc[t][1] = __builtin_amdgcn_mfma_f32_16x16x32_bf16(av, S.c1, acc[t][1], 0, 0, 0);
            acc[t][2] = __builtin_amdgcn_mfma_f32_16x16x32_bf16(av, S.c2, acc[t][2], 0, 0, 0);
            acc[t][3] = __builtin_amdgcn_mfma_f32_16x16x32_bf16(av, S.c3, acc[t][3], 0, 0, 0);
            accd[t]   = __builtin_amdgcn_mfma_f32_16x16x32_bf16(av, ones, accd[t], 0, 0, 0);
        }
    };

    __syncthreads();   // x tables visible
    Slot A, B;
    loadk(A, 0);
    for (int p = 0; p < 32; p += 2) {
        loadk(B, p + 1);                 // p <= 30 so p+1 <= 31 always valid
        compute(A);
        if (p + 2 < 32) loadk(A, p + 2);
        compute(B);
    }

    // ---- exchange: wave keeps tiles {half*2, half*2+1}, sends the others ----
#pragma unroll
    for (int j = 0; j < 2; ++j) {
        float* xw = &xred[wv][lane][0];
        if (half == 0) {          // send tile 2+j
            *(floatx4*)&xw[0]  = acc[2 + j][0];
            *(floatx4*)&xw[4]  = acc[2 + j][1];
            *(floatx4*)&xw[8]  = acc[2 + j][2];
            *(floatx4*)&xw[12] = acc[2 + j][3];
            *(floatx4*)&xw[16] = accd[2 + j];
        } else {                  // send tile j
            *(floatx4*)&xw[0]  = acc[j][0];
            *(floatx4*)&xw[4]  = acc[j][1];
            *(floatx4*)&xw[8]  = acc[j][2];
            *(floatx4*)&xw[12] = acc[j][3];
            *(floatx4*)&xw[16] = accd[j];
        }
        __syncthreads();
        const float* xr = &xred[wv ^ 1][lane][0];
        if (half == 0) {          // receive tile j
            acc[j][0] += *(const floatx4*)&xr[0];
            acc[j][1] += *(const floatx4*)&xr[4];
            acc[j][2] += *(const floatx4*)&xr[8];
            acc[j][3] += *(const floatx4*)&xr[12];
            accd[j]   += *(const floatx4*)&xr[16];
        } else {                  // receive tile 2+j
            acc[2 + j][0] += *(const floatx4*)&xr[0];
            acc[2 + j][1] += *(const floatx4*)&xr[4];
            acc[2 + j][2] += *(const floatx4*)&xr[8];
            acc[2 + j][3] += *(const floatx4*)&xr[12];
            accd[2 + j]   += *(const floatx4*)&xr[16];
        }
        __syncthreads();
    }

    // ---- epilogue: 2 owned tiles -> stage V, project, store ----
    const unsigned short* wtg = (const unsigned short*)(ws + WS_WT_OFF);

    auto epi = [&](const floatx4 (&a)[4], const floatx4 ad, float syt, int t, int tt) {
        const float sysq = syt * syt;
        const int   mrow = m0 + t * 16;
        float dt[4], ff[4];
#pragma unroll
        for (int reg = 0; reg < 4; ++reg) {
            const int m   = (lane >> 4) * 4 + reg;   // C/D map row
            const float ysq = __shfl(sysq, m, 64);   // lane m holds row m's y^2
            const float e   = EXP2F(-ysq);
            dt[reg] = ad[reg] * e;
            ff[reg] = e / (dt[reg] + 1e-8f);
        }
        unsigned short* vs = vstage[wv][tt];
#pragma unroll
        for (int reg = 0; reg < 4; ++reg) {
            const int m = (lane >> 4) * 4 + reg;
#pragma unroll
            for (int q = 0; q < 4; ++q) {
                const int c = q * 16 + l15;
                vs[(c >> 3) * 128 + m * 8 + (c & 7)] = f2bf(a[q][reg]);
            }
        }
        floatx4 pacc[8];
#pragma unroll
        for (int rt = 0; rt < 8; ++rt)
#pragma unroll
            for (int e = 0; e < 4; ++e) pacc[rt][e] = 0.0f;
#pragma unroll
        for (int s2 = 0; s2 < 2; ++s2) {
            const int ch = s2 * 4 + g2;
            const bf16x8 avp = *(const bf16x8*)&vs[ch * 128 + l15 * 8];
#pragma unroll
            for (int rt = 0; rt < 8; ++rt) {
                const bf16x8 bvp = *(const bf16x8*)&wtg[ch * 1024 + (rt * 16 + l15) * 8];
                pacc[rt] = __builtin_amdgcn_mfma_f32_16x16x32_bf16(avp, bvp, pacc[rt], 0, 0, 0);
            }
        }
#pragma unroll
        for (int rt = 0; rt < 8; ++rt) {
            const int r = rt * 16 + l15;
            const float w0v = W[r * 65];
            const float bv  = bias[r];
#pragma unroll
            for (int reg = 0; reg < 4; ++reg) {
                const int m = (lane >> 4) * 4 + reg;
                out[((size_t)(mrow + m) * BATCH + b) * RDIM + r]
                    = pacc[rt][reg] * ff[reg] + dt[reg] * w0v + bv;
            }
        }
    };

    if (half == 0) {
        epi(acc[0], accd[0], syv[0], 0, 0);
        epi(acc[1], accd[1], syv[1], 1, 1);
    } else {
        epi(acc[2], accd[2], syv[2], 2, 0);
        epi(acc[3], accd[3], syv[3], 3, 1);
    }
}

extern "C" void kernel_launch(void* const* d_in, const int* in_sizes, int n_in,
                              void* d_out, int out_size, void* d_ws, size_t ws_size,
                              hipStream_t stream) {
    const float* ci   = (const float*)d_in[0];  // context_in  (N,B,1)
    const float* co   = (const float*)d_in[1];  // context_out (N,B,64)
    const float* ti   = (const float*)d_in[2];  // target_in   (M,B,1)
    const float* ls   = (const float*)d_in[3];  // lengthscale (1,)
    const float* W    = (const float*)d_in[4];  // (128,65)
    const float* bias = (const float*)d_in[5];  // (128,)
    float* o = (float*)d_out;                   // (M,B,128)
    (void)in_sizes; (void)n_in; (void)out_size; (void)ws_size;

    convdeepset_prep<<<1153, 256, 0, stream>>>(ci, co, ls, W, (unsigned char*)d_ws);
    convdeepset_main<<<512, 256, 0, stream>>>(
        ti, ls, W, bias, (const unsigned char*)d_ws, o);
}